// Round 7
// baseline (2521.198 us; speedup 1.0000x reference)
//
#include <hip/hip_runtime.h>
#include <cstdint>
#include <cstddef>
#include <cmath>

#define H  2048
#define BB 2048   // batch
#define TT 64     // time steps
#define NC 10     // classes

typedef __bf16 bf16;
typedef bf16  bf16x8 __attribute__((ext_vector_type(8)));
typedef float f32x4  __attribute__((ext_vector_type(4)));

// ---------------------------------------------------------------------------
// async global->LDS, 16B per lane. LDS dest is wave-uniform base + lane*16;
// global source is per-lane.
// ---------------------------------------------------------------------------
__device__ __forceinline__ void load_lds16(const void* g, void* l) {
    __builtin_amdgcn_global_load_lds(
        (__attribute__((address_space(1))) void*)(void*)g,
        (__attribute__((address_space(3))) void*)l,
        16, 0, 0);
}

// ---------------------------------------------------------------------------
// FRAG-MAJOR layout (W_hh and S, since R12).
// For a matrix [R rows][H k-cols] (bf16):
//   subtile (r16, k32) = 16 rows x 32 k = 1024 B at id = r16*(H/32) + k32.
//   lane-slot l (16 B) holds M[r16*16 + (l&15)][k32*32 + (l>>4)*8 .. +8]
// = exactly the v_mfma_f32_16x16x32_bf16 A/B fragment, so a wave's frag load
// is ONE coalesced 1 KB segment: base + id*512 + lane*8 (bf16 elems).
// ---------------------------------------------------------------------------
__global__ void w_shuffle_kernel(const float* __restrict__ Whh,
                                 bf16* __restrict__ Wshuf) {
    int tid = blockIdx.x * blockDim.x + threadIdx.x;   // 0 .. H*H/8-1
    int sub = tid >> 6;          // subtile id
    int l   = tid & 63;          // dest lane slot
    int n16 = sub >> 6;          // 0..127
    int k32 = sub & 63;          // 0..63
    int n = n16 * 16 + (l & 15);
    int k = k32 * 32 + (l >> 4) * 8;
    const float* src = Whh + (size_t)n * H + k;
    bf16x8 o;
#pragma unroll
    for (int j = 0; j < 8; ++j) o[j] = (bf16)src[j];
    *(bf16x8*)(Wshuf + (size_t)tid * 8) = o;
}

// ---------------------------------------------------------------------------
// t = 0: S[b,i] = tanh(Whx[i]*x[b,0] + bh[i]), written FRAG-MAJOR.
// ---------------------------------------------------------------------------
__global__ void rnn_init(const float* __restrict__ x,     // [B, T]
                         const float* __restrict__ Whx,   // [H]
                         const float* __restrict__ bh,    // [H]
                         bf16* __restrict__ S) {          // frag-major
    int b  = blockIdx.x;
    int i0 = threadIdx.x * 8;
    float xv = x[(size_t)b * TT];
    bf16x8 o;
#pragma unroll
    for (int j = 0; j < 8; ++j)
        o[j] = (bf16)tanhf(Whx[i0 + j] * xv + bh[i0 + j]);
    size_t sub  = (size_t)(b >> 4) * 64 + (i0 >> 5);
    size_t slot = (size_t)(b & 15) | (size_t)(((i0 >> 3) & 3) << 4);
    *(bf16x8*)(S + (sub * 64 + slot) * 8) = o;
}

// ---------------------------------------------------------------------------
// One RNN time step, Round-17 "2-way split-K: 8 waves x 64x64 tiles":
//   Sw[b,i] = tanh( sum_k Sr[b,k]*W[i,k] + Whx[i]*x[b,t] + bh[i] )
//
// R16 post-mortem: 64x64 wave tiles (2x LDS read amplification, the
// geometry optimum) regressed at 4 waves because 1 wave/SIMD has no TLP to
// hide phase bubbles. R15 had TLP but 3x amplification. R17 gets BOTH:
//
//   - 8 waves, wave w = (kh = w>>2, s = w&3): kh picks a K-half (chunks
//     0..31 vs 32..63), s picks a 64x64 quadrant (qm = s&1, qn = s>>1) of
//     the 128x128 block tile. grid 256 = 1 block/CU, zero tail.
//   - 32 phases, each = 1 k32-chunk per K-half. Stage/phase = 32 KB unique
//     (A-lo, A-hi, B-lo, B-hi; 4 segs/wave). Per wave COMPUTE = 8 KB LDS
//     read for 16 MFMAs -> amplification 2x. Per-phase: LDS 96 KB (857cy),
//     MFMA 620cy, VMEM 32 KB (571cy) — balanced at 2 waves/SIMD.
//   - R15 skeleton inherited: 4-slot ring (4 x 32 KB), counted vmcnt(8)
//     never 0 in-loop, raw s_barrier, 3-phase-deep prefetch, setprio on
//     MFMA, XCD-owns-n (W panel L2-resident), frag-major operands.
//   - Split-K pair reduction: wave (0,s) donates acc fm{2,3}, wave (1,s)
//     donates fm{0,1} into slots 0/1 (64 KB; quiescent: phase 31 waited
//     vmcnt(0), stragglers only read slot 3); one __syncthreads; partner
//     adds (f32 + is commutative; association diff ~1e-7 << bf16 floor).
//     Each wave then epilogues its OWN 32x64 rows — full 8-wave tanh
//     parallelism. Transpose scratch = slot 2 (8 x 4 KB, wave-private).
// ---------------------------------------------------------------------------
#define PH_WAIT(NSTR) asm volatile("s_waitcnt vmcnt(" NSTR ")" ::: "memory")
#define SBAR0()       __builtin_amdgcn_sched_barrier(0)

__launch_bounds__(512, 2)
__global__ void rnn_step(const float* __restrict__ x,     // [B, T]
                         const float* __restrict__ Whx,   // [H]
                         const float* __restrict__ bh,    // [H]
                         const bf16*  __restrict__ Wshuf, // frag-major W_hh
                         const bf16*  __restrict__ Sr,    // frag-major S read
                         bf16* __restrict__ Sw,           // frag-major S write
                         int t) {
    // ring slot = 32 segs x 1 KB:
    //   segs  0..7  = A m16 0..7, chunk-lo   segs  8..15 = B n16 0..7, lo
    //   segs 16..23 = A m16 0..7, chunk-hi   segs 24..31 = B n16 0..7, hi
    __shared__ __align__(16) char Ls[4][32768];   // 128 KB -> 1 block/CU

    const int tid  = threadIdx.x;
    const int w    = tid >> 6;          // wave 0..7
    const int lane = tid & 63;
    const int lrow = lane & 15;
    const int quad = lane >> 4;

    // XCD-owns-n mapping: XCD x covers n-cols [x*256, x*256+256).
    const int xcd = blockIdx.x & 7;
    const int loc = blockIdx.x >> 3;               // 0..31
    const int bm0 = (loc >> 1) * 128;              // batch-row tile origin
    const int bn0 = xcd * 256 + (loc & 1) * 128;   // hidden-col tile origin

    const int kh   = w >> 2;                       // K-half (0: k<1024)
    const int s    = w & 3;                        // quadrant id
    const int qm   = s & 1;                        // m-quadrant (64 rows)
    const int qn   = s >> 1;                       // n-quadrant (64 cols)
    const int cn0  = bn0 + qn * 64;                // wave's first col
    const int kh16 = kh * 16;                      // seg offset of own half

    // staging sources (per wave): wave w owns A m16 subtile (bm0>>4)+w and
    // B n16 subtile (bn0>>4)+w, BOTH k-halves. 1 KB per k32, +lane*16B.
    const char* srcA = (const char*)Sr +
        ((size_t)((bm0 >> 4) + w) * 64) * 1024 + (size_t)lane * 16;
    const char* srcB = (const char*)Wshuf +
        ((size_t)((bn0 >> 4) + w) * 64) * 1024 + (size_t)lane * 16;

    f32x4 acc[4][4];
#pragma unroll
    for (int i = 0; i < 4; ++i)
#pragma unroll
        for (int j = 0; j < 4; ++j) acc[i][j] = (f32x4){0.f, 0.f, 0.f, 0.f};

    // ---- issue section for phase pp into ring slot RI (4 VMEM ops) ----
#define ISSUE(RI, pp)                                                        \
    {                                                                        \
        load_lds16(srcA + (size_t)(pp) * 1024,        &Ls[RI][w * 1024]);    \
        load_lds16(srcB + (size_t)(pp) * 1024,        &Ls[RI][(8 + w) * 1024]); \
        load_lds16(srcA + (size_t)(32 + (pp)) * 1024, &Ls[RI][(16 + w) * 1024]); \
        load_lds16(srcB + (size_t)(32 + (pp)) * 1024, &Ls[RI][(24 + w) * 1024]); \
    }

    // ---- compute section for phase p using ring slot RI (16 MFMA) ----
#define COMPUTE(RI)                                                          \
    {                                                                        \
        bf16x8 Af[4], Bf[4];                                                 \
        _Pragma("unroll")                                                    \
        for (int fm = 0; fm < 4; ++fm)                                       \
            Af[fm] = *(const bf16x8*)&Ls[RI]                                 \
                [(kh16 + qm * 4 + fm) * 1024 + lane * 16];                   \
        _Pragma("unroll")                                                    \
        for (int fn = 0; fn < 4; ++fn)                                       \
            Bf[fn] = *(const bf16x8*)&Ls[RI]                                 \
                [(kh16 + 8 + qn * 4 + fn) * 1024 + lane * 16];               \
        __builtin_amdgcn_s_setprio(1);                                       \
        _Pragma("unroll")                                                    \
        for (int fm = 0; fm < 4; ++fm)                                       \
            _Pragma("unroll")                                                \
            for (int fn = 0; fn < 4; ++fn)                                   \
                acc[fm][fn] = __builtin_amdgcn_mfma_f32_16x16x32_bf16(       \
                    Af[fm], Bf[fn], acc[fm][fn], 0, 0, 0);                   \
        __builtin_amdgcn_s_setprio(0);                                       \
    }

#define PHASE(RI, RN, p, WNSTR, DOISS)                                       \
    {                                                                        \
        PH_WAIT(WNSTR);                                                      \
        SBAR0();                                                             \
        __builtin_amdgcn_s_barrier();                                        \
        SBAR0();                                                             \
        if (DOISS) ISSUE(RN, (p) + 3);                                       \
        SBAR0();                                                             \
        COMPUTE(RI);                                                         \
    }

    // prologue: issue phases 0,1,2 into slots 0,1,2 (order pinned)
    ISSUE(0, 0); SBAR0();
    ISSUE(1, 1); SBAR0();
    ISSUE(2, 2); SBAR0();

    // main loop: phases 0..27 (7 macro-iters x 4), steady wait = 8
#pragma unroll 1
    for (int q = 0; q < 7; ++q) {
        int p = 4 * q;
        PHASE(0, 3, p + 0, "8", true);
        PHASE(1, 0, p + 1, "8", true);
        PHASE(2, 1, p + 2, "8", true);
        PHASE(3, 2, p + 3, "8", true);
    }
    // peeled tail: phases 28..31
    PHASE(0, 3, 28, "8", true);    // issues phase 31
    PHASE(1, 0, 29, "8", false);
    PHASE(2, 1, 30, "4", false);
    PHASE(3, 2, 31, "0", false);

#undef PHASE
#undef COMPUTE
#undef ISSUE

    // ---- split-K pair reduction (slots 0-1; quiescent after vmcnt(0)) ----
    // wave (kh=0,s) donates fm{2,3} at pairbase+0; (kh=1,s) donates fm{0,1}
    // at pairbase+8K. After sync each wave adds partner's donation to the
    // half it keeps: kh=0 keeps rows fm{0,1}, kh=1 keeps rows fm{2,3}.
    {
        char* red = &Ls[0][0];
        const int pairbase = s * 16384;
        if (kh == 0) {
#pragma unroll
            for (int fm = 2; fm < 4; ++fm)
#pragma unroll
                for (int fn = 0; fn < 4; ++fn)
                    *(f32x4*)&red[pairbase + ((fm - 2) * 4 + fn) * 1024 +
                                  lane * 16] = acc[fm][fn];
        } else {
#pragma unroll
            for (int fm = 0; fm < 2; ++fm)
#pragma unroll
                for (int fn = 0; fn < 4; ++fn)
                    *(f32x4*)&red[pairbase + 8192 + (fm * 4 + fn) * 1024 +
                                  lane * 16] = acc[fm][fn];
        }
        __syncthreads();
        if (kh == 0) {
#pragma unroll
            for (int fm = 0; fm < 2; ++fm)
#pragma unroll
                for (int fn = 0; fn < 4; ++fn)
                    acc[fm][fn] += *(const f32x4*)&red[pairbase + 8192 +
                        (fm * 4 + fn) * 1024 + lane * 16];
        } else {
#pragma unroll
            for (int fm = 2; fm < 4; ++fm)
#pragma unroll
                for (int fn = 0; fn < 4; ++fn)
                    acc[fm][fn] += *(const f32x4*)&red[pairbase +
                        ((fm - 2) * 4 + fn) * 1024 + lane * 16];
        }
    }

    // ---- epilogue on OWNED rows: z += Whx*x + bh; tanh; transpose ----
    // acc layout (16x16x32): col = lane&15, row = quad*4 + reg [m89-verified]
    // Owned fm set = {kh*2, kh*2+1} -> rows bm0+qm*64 + fm*16.. (+16).
    // Transpose scratch: slot 2, wave-private 32 rows x 128 B, XOR-swizzled.
    bf16* Lw = (bf16*)&Ls[2][0] + (size_t)w * 2048;
#pragma unroll
    for (int fml = 0; fml < 2; ++fml) {
        const int fm = kh * 2 + fml;
        int rb = bm0 + qm * 64 + fm * 16 + quad * 4;
        float xv[4];
#pragma unroll
        for (int r = 0; r < 4; ++r) xv[r] = x[(size_t)(rb + r) * TT + t];
#pragma unroll
        for (int fn = 0; fn < 4; ++fn) {
            int col = cn0 + fn * 16 + lrow;
            float wx = Whx[col], bb = bh[col];
            int cbyte = (fn * 16 + lrow) * 2;
#pragma unroll
            for (int r = 0; r < 4; ++r) {
                int row_l = fml * 16 + quad * 4 + r;
                float z = acc[fm][fn][r] + wx * xv[r] + bb;
                *(bf16*)((char*)Lw + row_l * 128 +
                         (cbyte ^ ((row_l & 7) << 4))) = (bf16)tanhf(z);
            }
        }
    }
    // read own wave's tile in frag-slot order; 16B coalesced global stores.
#pragma unroll
    for (int fml = 0; fml < 2; ++fml) {
        const int fm = kh * 2 + fml;
#pragma unroll
        for (int kc = 0; kc < 2; ++kc) {
            int row_l = fml * 16 + lrow;
            int cb    = (kc * 64 + quad * 16) ^ ((row_l & 7) << 4);
            bf16x8 v = *(const bf16x8*)((const char*)Lw + row_l * 128 + cb);
            size_t sub = (size_t)((bm0 >> 4) + qm * 4 + fm) * 64 +
                         (cn0 >> 5) + kc;
            *(bf16x8*)(Sw + (sub * 64 + lane) * 8) = v;
        }
    }
}

// ---------------------------------------------------------------------------
// out[b,c] = sum_h Why[h,c] * S[b,h] + bp[c]   (S frag-major)
// ---------------------------------------------------------------------------
__global__ void out_proj(const bf16* __restrict__ S,
                         const float* __restrict__ Why,   // [H, C]
                         const float* __restrict__ bp,    // [C]
                         float* __restrict__ out) {       // [B, C]
    int b = blockIdx.x, tid = threadIdx.x;
    int h0 = tid * 8;                                     // 256*8 = H exactly
    size_t sub  = (size_t)(b >> 4) * 64 + (h0 >> 5);
    size_t slot = (size_t)(b & 15) | (size_t)(((h0 >> 3) & 3) << 4);
    bf16x8 v = *(const bf16x8*)(S + (sub * 64 + slot) * 8);
    float p[NC];
#pragma unroll
    for (int c = 0; c < NC; ++c) p[c] = 0.f;
#pragma unroll
    for (int j = 0; j < 8; ++j) {
        float s = (float)v[j];
        const float* wr = Why + (size_t)(h0 + j) * NC;
#pragma unroll
        for (int c = 0; c < NC; ++c) p[c] += s * wr[c];
    }
    __shared__ float red[256 * NC];
#pragma unroll
    for (int c = 0; c < NC; ++c) red[tid * NC + c] = p[c];
    __syncthreads();
    for (int s = 128; s > 0; s >>= 1) {
        if (tid < s)
#pragma unroll
            for (int c = 0; c < NC; ++c) red[tid * NC + c] += red[(tid + s) * NC + c];
        __syncthreads();
    }
    if (tid < NC) out[(size_t)b * NC + tid] = red[tid] + bp[tid];
}

// ---------------------------------------------------------------------------
extern "C" void kernel_launch(void* const* d_in, const int* in_sizes, int n_in,
                              void* d_out, int out_size, void* d_ws, size_t ws_size,
                              hipStream_t stream) {
    const float* x   = (const float*)d_in[0];   // [B, T]
    const float* Whx = (const float*)d_in[1];   // [H, 1]
    const float* Whh = (const float*)d_in[2];   // [H, H]
    const float* Why = (const float*)d_in[3];   // [H, C]
    const float* bh  = (const float*)d_in[4];   // [H, 1]
    const float* bp  = (const float*)d_in[5];   // [C, 1]
    float* out = (float*)d_out;

    // workspace: Wshuf (8 MB) | S0 (8 MB) | S1 (8 MB)   (all frag-major)
    bf16* Wshuf = (bf16*)d_ws;
    bf16* S0 = (bf16*)((char*)d_ws + (size_t)8 * 1024 * 1024);
    bf16* S1 = (bf16*)((char*)d_ws + (size_t)16 * 1024 * 1024);

    hipLaunchKernelGGL(w_shuffle_kernel, dim3((H * H / 8) / 256), dim3(256),
                       0, stream, Whh, Wshuf);

    // t = 0 writes S1; step t reads (t&1 ? S1 : S0), writes the other.
    hipLaunchKernelGGL(rnn_init, dim3(BB), dim3(256), 0, stream, x, Whx, bh, S1);

    for (int t = 1; t < TT; ++t) {
        const bf16* Srd = (t & 1) ? S1 : S0;
        bf16*       Swr = (t & 1) ? S0 : S1;
        hipLaunchKernelGGL(rnn_step, dim3(256), dim3(512), 0, stream,
                           x, Whx, bh, Wshuf, Srd, Swr, t);
    }

    // t=63 (odd) wrote S0
    hipLaunchKernelGGL(out_proj, dim3(BB), dim3(256), 0, stream, S0, Why, bp, out);
}

// Round 8
// 1525.961 us; speedup vs baseline: 1.6522x; 1.6522x over previous
//
#include <hip/hip_runtime.h>
#include <cstdint>
#include <cstddef>
#include <cmath>

#define H  2048
#define BB 2048   // batch
#define TT 64     // time steps
#define NC 10     // classes

typedef __bf16 bf16;
typedef bf16  bf16x8 __attribute__((ext_vector_type(8)));
typedef float f32x4  __attribute__((ext_vector_type(4)));

// ---------------------------------------------------------------------------
// async global->LDS, 16B per lane. LDS dest is wave-uniform base + lane*16;
// global source is per-lane.
// ---------------------------------------------------------------------------
__device__ __forceinline__ void load_lds16(const void* g, void* l) {
    __builtin_amdgcn_global_load_lds(
        (__attribute__((address_space(1))) void*)(void*)g,
        (__attribute__((address_space(3))) void*)l,
        16, 0, 0);
}

// ---------------------------------------------------------------------------
// FRAG-MAJOR layout (W_hh and S, since R12).
// For a matrix [R rows][H k-cols] (bf16):
//   subtile (r16, k32) = 16 rows x 32 k = 1024 B at id = r16*(H/32) + k32.
//   lane-slot l (16 B) holds M[r16*16 + (l&15)][k32*32 + (l>>4)*8 .. +8]
// = exactly the v_mfma_f32_16x16x32_bf16 A/B fragment, so a wave's frag load
// is ONE coalesced 1 KB segment: base + id*512 + lane*8 (bf16 elems).
// ---------------------------------------------------------------------------
__global__ void w_shuffle_kernel(const float* __restrict__ Whh,
                                 bf16* __restrict__ Wshuf) {
    int tid = blockIdx.x * blockDim.x + threadIdx.x;   // 0 .. H*H/8-1
    int sub = tid >> 6;          // subtile id
    int l   = tid & 63;          // dest lane slot
    int n16 = sub >> 6;          // 0..127
    int k32 = sub & 63;          // 0..63
    int n = n16 * 16 + (l & 15);
    int k = k32 * 32 + (l >> 4) * 8;
    const float* src = Whh + (size_t)n * H + k;
    bf16x8 o;
#pragma unroll
    for (int j = 0; j < 8; ++j) o[j] = (bf16)src[j];
    *(bf16x8*)(Wshuf + (size_t)tid * 8) = o;
}

// ---------------------------------------------------------------------------
// t = 0: S[b,i] = tanh(Whx[i]*x[b,0] + bh[i]), written FRAG-MAJOR.
// ---------------------------------------------------------------------------
__global__ void rnn_init(const float* __restrict__ x,     // [B, T]
                         const float* __restrict__ Whx,   // [H]
                         const float* __restrict__ bh,    // [H]
                         bf16* __restrict__ S) {          // frag-major
    int b  = blockIdx.x;
    int i0 = threadIdx.x * 8;
    float xv = x[(size_t)b * TT];
    bf16x8 o;
#pragma unroll
    for (int j = 0; j < 8; ++j)
        o[j] = (bf16)tanhf(Whx[i0 + j] * xv + bh[i0 + j]);
    size_t sub  = (size_t)(b >> 4) * 64 + (i0 >> 5);
    size_t slot = (size_t)(b & 15) | (size_t)(((i0 >> 3) & 3) << 4);
    *(bf16x8*)(S + (sub * 64 + slot) * 8) = o;
}

// ---------------------------------------------------------------------------
// One RNN time step, Round-18 = Round-17 with the rule-#20 violation fixed:
//   Sw[b,i] = tanh( sum_k Sr[b,k]*W[i,k] + Whx[i]*x[b,t] + bh[i] )
//
// R17 post-mortem: the epilogue indexed acc[kh*2+fml] with RUNTIME kh ->
// the whole acc array demoted to scratch (VGPR 88, WRITE_SIZE 118 MB/step,
// MfmaUtil 0.16%). Structure was never actually measured. R18 keeps the
// identical split-K structure but all acc accesses are static:
//   - donate/own handled in if(kh==0)/else branches with literal indices
//   - epilogue reads a statically-indexed own[2][4]
//   - kh*2+fml appears only in ADDRESS arithmetic (legal)
//
// Structure (unchanged from R17):
//   - 8 waves, wave w = (kh = w>>2, s = w&3): kh picks a K-half, s picks a
//     64x64 quadrant (qm = s&1, qn = s>>1) of the 128x128 block tile.
//     grid 256 = 1 block/CU. 2x LDS read amplification + 2 waves/SIMD TLP.
//   - 32 phases x (1 k32-chunk per K-half). Stage/phase = 32 KB unique.
//     Per-phase: LDS 96 KB (857cy), MFMA 620cy, VMEM 32 KB (571cy).
//   - 4-slot ring (4 x 32 KB), counted vmcnt(8) never 0 in-loop, raw
//     s_barrier, 3-phase-deep prefetch, setprio on MFMA, XCD-owns-n,
//     frag-major operands.
//   - Split-K pair reduction via LDS slots 0/1, one __syncthreads, then
//     8-wave-parallel epilogue on owned 32x64 rows.
// ---------------------------------------------------------------------------
#define PH_WAIT(NSTR) asm volatile("s_waitcnt vmcnt(" NSTR ")" ::: "memory")
#define SBAR0()       __builtin_amdgcn_sched_barrier(0)

__launch_bounds__(512, 2)
__global__ void rnn_step(const float* __restrict__ x,     // [B, T]
                         const float* __restrict__ Whx,   // [H]
                         const float* __restrict__ bh,    // [H]
                         const bf16*  __restrict__ Wshuf, // frag-major W_hh
                         const bf16*  __restrict__ Sr,    // frag-major S read
                         bf16* __restrict__ Sw,           // frag-major S write
                         int t) {
    // ring slot = 32 segs x 1 KB:
    //   segs  0..7  = A m16 0..7, chunk-lo   segs  8..15 = B n16 0..7, lo
    //   segs 16..23 = A m16 0..7, chunk-hi   segs 24..31 = B n16 0..7, hi
    __shared__ __align__(16) char Ls[4][32768];   // 128 KB -> 1 block/CU

    const int tid  = threadIdx.x;
    const int w    = tid >> 6;          // wave 0..7
    const int lane = tid & 63;
    const int lrow = lane & 15;
    const int quad = lane >> 4;

    // XCD-owns-n mapping: XCD x covers n-cols [x*256, x*256+256).
    const int xcd = blockIdx.x & 7;
    const int loc = blockIdx.x >> 3;               // 0..31
    const int bm0 = (loc >> 1) * 128;              // batch-row tile origin
    const int bn0 = xcd * 256 + (loc & 1) * 128;   // hidden-col tile origin

    const int kh   = w >> 2;                       // K-half (0: k<1024)
    const int s    = w & 3;                        // quadrant id
    const int qm   = s & 1;                        // m-quadrant (64 rows)
    const int qn   = s >> 1;                       // n-quadrant (64 cols)
    const int cn0  = bn0 + qn * 64;                // wave's first col
    const int kh16 = kh * 16;                      // seg offset of own half

    // staging sources (per wave): wave w owns A m16 subtile (bm0>>4)+w and
    // B n16 subtile (bn0>>4)+w, BOTH k-halves. 1 KB per k32, +lane*16B.
    const char* srcA = (const char*)Sr +
        ((size_t)((bm0 >> 4) + w) * 64) * 1024 + (size_t)lane * 16;
    const char* srcB = (const char*)Wshuf +
        ((size_t)((bn0 >> 4) + w) * 64) * 1024 + (size_t)lane * 16;

    f32x4 acc[4][4];
#pragma unroll
    for (int i = 0; i < 4; ++i)
#pragma unroll
        for (int j = 0; j < 4; ++j) acc[i][j] = (f32x4){0.f, 0.f, 0.f, 0.f};

    // ---- issue section for phase pp into ring slot RI (4 VMEM ops) ----
#define ISSUE(RI, pp)                                                        \
    {                                                                        \
        load_lds16(srcA + (size_t)(pp) * 1024,        &Ls[RI][w * 1024]);    \
        load_lds16(srcB + (size_t)(pp) * 1024,        &Ls[RI][(8 + w) * 1024]); \
        load_lds16(srcA + (size_t)(32 + (pp)) * 1024, &Ls[RI][(16 + w) * 1024]); \
        load_lds16(srcB + (size_t)(32 + (pp)) * 1024, &Ls[RI][(24 + w) * 1024]); \
    }

    // ---- compute section for phase p using ring slot RI (16 MFMA) ----
#define COMPUTE(RI)                                                          \
    {                                                                        \
        bf16x8 Af[4], Bf[4];                                                 \
        _Pragma("unroll")                                                    \
        for (int fm = 0; fm < 4; ++fm)                                       \
            Af[fm] = *(const bf16x8*)&Ls[RI]                                 \
                [(kh16 + qm * 4 + fm) * 1024 + lane * 16];                   \
        _Pragma("unroll")                                                    \
        for (int fn = 0; fn < 4; ++fn)                                       \
            Bf[fn] = *(const bf16x8*)&Ls[RI]                                 \
                [(kh16 + 8 + qn * 4 + fn) * 1024 + lane * 16];               \
        __builtin_amdgcn_s_setprio(1);                                       \
        _Pragma("unroll")                                                    \
        for (int fm = 0; fm < 4; ++fm)                                       \
            _Pragma("unroll")                                                \
            for (int fn = 0; fn < 4; ++fn)                                   \
                acc[fm][fn] = __builtin_amdgcn_mfma_f32_16x16x32_bf16(       \
                    Af[fm], Bf[fn], acc[fm][fn], 0, 0, 0);                   \
        __builtin_amdgcn_s_setprio(0);                                       \
    }

#define PHASE(RI, RN, p, WNSTR, DOISS)                                       \
    {                                                                        \
        PH_WAIT(WNSTR);                                                      \
        SBAR0();                                                             \
        __builtin_amdgcn_s_barrier();                                        \
        SBAR0();                                                             \
        if (DOISS) ISSUE(RN, (p) + 3);                                       \
        SBAR0();                                                             \
        COMPUTE(RI);                                                         \
    }

    // prologue: issue phases 0,1,2 into slots 0,1,2 (order pinned)
    ISSUE(0, 0); SBAR0();
    ISSUE(1, 1); SBAR0();
    ISSUE(2, 2); SBAR0();

    // main loop: phases 0..27 (7 macro-iters x 4), steady wait = 8
#pragma unroll 1
    for (int q = 0; q < 7; ++q) {
        int p = 4 * q;
        PHASE(0, 3, p + 0, "8", true);
        PHASE(1, 0, p + 1, "8", true);
        PHASE(2, 1, p + 2, "8", true);
        PHASE(3, 2, p + 3, "8", true);
    }
    // peeled tail: phases 28..31
    PHASE(0, 3, 28, "8", true);    // issues phase 31
    PHASE(1, 0, 29, "8", false);
    PHASE(2, 1, 30, "4", false);
    PHASE(3, 2, 31, "0", false);

#undef PHASE
#undef COMPUTE
#undef ISSUE

    // ---- split-K pair reduction (slots 0-1; quiescent after vmcnt(0)) ----
    // ALL acc indices below are compile-time constants (rule #20).
    // kh=0 donates fm{2,3}; kh=1 donates fm{0,1}; own = kept + partner.
    char* red = &Ls[0][0];
    const int pairbase = s * 16384;
    if (kh == 0) {
#pragma unroll
        for (int fml = 0; fml < 2; ++fml)
#pragma unroll
            for (int fn = 0; fn < 4; ++fn)
                *(f32x4*)&red[pairbase + (fml * 4 + fn) * 1024 + lane * 16] =
                    acc[2 + fml][fn];
    } else {
#pragma unroll
        for (int fml = 0; fml < 2; ++fml)
#pragma unroll
            for (int fn = 0; fn < 4; ++fn)
                *(f32x4*)&red[pairbase + 8192 + (fml * 4 + fn) * 1024 +
                              lane * 16] = acc[fml][fn];
    }
    __syncthreads();
    f32x4 own[2][4];
    if (kh == 0) {
#pragma unroll
        for (int fml = 0; fml < 2; ++fml)
#pragma unroll
            for (int fn = 0; fn < 4; ++fn)
                own[fml][fn] = acc[fml][fn] + *(const f32x4*)&red[pairbase +
                    8192 + (fml * 4 + fn) * 1024 + lane * 16];
    } else {
#pragma unroll
        for (int fml = 0; fml < 2; ++fml)
#pragma unroll
            for (int fn = 0; fn < 4; ++fn)
                own[fml][fn] = acc[2 + fml][fn] + *(const f32x4*)&red[pairbase +
                    (fml * 4 + fn) * 1024 + lane * 16];
    }

    // ---- epilogue on OWNED rows: z += Whx*x + bh; tanh; transpose ----
    // acc layout (16x16x32): col = lane&15, row = quad*4 + reg [m89-verified]
    // Owned global fm = kh*2 + fml (address math only; own[] is static-idx).
    // Transpose scratch: slot 2, wave-private 32 rows x 128 B, XOR-swizzled.
    bf16* Lw = (bf16*)&Ls[2][0] + (size_t)w * 2048;
#pragma unroll
    for (int fml = 0; fml < 2; ++fml) {
        int rb = bm0 + qm * 64 + (kh * 2 + fml) * 16 + quad * 4;
        float xv[4];
#pragma unroll
        for (int r = 0; r < 4; ++r) xv[r] = x[(size_t)(rb + r) * TT + t];
#pragma unroll
        for (int fn = 0; fn < 4; ++fn) {
            int col = cn0 + fn * 16 + lrow;
            float wx = Whx[col], bb = bh[col];
            int cbyte = (fn * 16 + lrow) * 2;
#pragma unroll
            for (int r = 0; r < 4; ++r) {
                int row_l = fml * 16 + quad * 4 + r;
                float z = own[fml][fn][r] + wx * xv[r] + bb;
                *(bf16*)((char*)Lw + row_l * 128 +
                         (cbyte ^ ((row_l & 7) << 4))) = (bf16)tanhf(z);
            }
        }
    }
    // read own wave's tile in frag-slot order; 16B coalesced global stores.
#pragma unroll
    for (int fml = 0; fml < 2; ++fml) {
#pragma unroll
        for (int kc = 0; kc < 2; ++kc) {
            int row_l = fml * 16 + lrow;
            int cb    = (kc * 64 + quad * 16) ^ ((row_l & 7) << 4);
            bf16x8 v = *(const bf16x8*)((const char*)Lw + row_l * 128 + cb);
            size_t sub = (size_t)((bm0 >> 4) + qm * 4 + kh * 2 + fml) * 64 +
                         (cn0 >> 5) + kc;
            *(bf16x8*)(Sw + (sub * 64 + lane) * 8) = v;
        }
    }
}

// ---------------------------------------------------------------------------
// out[b,c] = sum_h Why[h,c] * S[b,h] + bp[c]   (S frag-major)
// ---------------------------------------------------------------------------
__global__ void out_proj(const bf16* __restrict__ S,
                         const float* __restrict__ Why,   // [H, C]
                         const float* __restrict__ bp,    // [C]
                         float* __restrict__ out) {       // [B, C]
    int b = blockIdx.x, tid = threadIdx.x;
    int h0 = tid * 8;                                     // 256*8 = H exactly
    size_t sub  = (size_t)(b >> 4) * 64 + (h0 >> 5);
    size_t slot = (size_t)(b & 15) | (size_t)(((h0 >> 3) & 3) << 4);
    bf16x8 v = *(const bf16x8*)(S + (sub * 64 + slot) * 8);
    float p[NC];
#pragma unroll
    for (int c = 0; c < NC; ++c) p[c] = 0.f;
#pragma unroll
    for (int j = 0; j < 8; ++j) {
        float s = (float)v[j];
        const float* wr = Why + (size_t)(h0 + j) * NC;
#pragma unroll
        for (int c = 0; c < NC; ++c) p[c] += s * wr[c];
    }
    __shared__ float red[256 * NC];
#pragma unroll
    for (int c = 0; c < NC; ++c) red[tid * NC + c] = p[c];
    __syncthreads();
    for (int s = 128; s > 0; s >>= 1) {
        if (tid < s)
#pragma unroll
            for (int c = 0; c < NC; ++c) red[tid * NC + c] += red[(tid + s) * NC + c];
        __syncthreads();
    }
    if (tid < NC) out[(size_t)b * NC + tid] = red[tid] + bp[tid];
}

// ---------------------------------------------------------------------------
extern "C" void kernel_launch(void* const* d_in, const int* in_sizes, int n_in,
                              void* d_out, int out_size, void* d_ws, size_t ws_size,
                              hipStream_t stream) {
    const float* x   = (const float*)d_in[0];   // [B, T]
    const float* Whx = (const float*)d_in[1];   // [H, 1]
    const float* Whh = (const float*)d_in[2];   // [H, H]
    const float* Why = (const float*)d_in[3];   // [H, C]
    const float* bh  = (const float*)d_in[4];   // [H, 1]
    const float* bp  = (const float*)d_in[5];   // [C, 1]
    float* out = (float*)d_out;

    // workspace: Wshuf (8 MB) | S0 (8 MB) | S1 (8 MB)   (all frag-major)
    bf16* Wshuf = (bf16*)d_ws;
    bf16* S0 = (bf16*)((char*)d_ws + (size_t)8 * 1024 * 1024);
    bf16* S1 = (bf16*)((char*)d_ws + (size_t)16 * 1024 * 1024);

    hipLaunchKernelGGL(w_shuffle_kernel, dim3((H * H / 8) / 256), dim3(256),
                       0, stream, Whh, Wshuf);

    // t = 0 writes S1; step t reads (t&1 ? S1 : S0), writes the other.
    hipLaunchKernelGGL(rnn_init, dim3(BB), dim3(256), 0, stream, x, Whx, bh, S1);

    for (int t = 1; t < TT; ++t) {
        const bf16* Srd = (t & 1) ? S1 : S0;
        bf16*       Swr = (t & 1) ? S0 : S1;
        hipLaunchKernelGGL(rnn_step, dim3(256), dim3(512), 0, stream,
                           x, Whx, bh, Wshuf, Srd, Swr, t);
    }

    // t=63 (odd) wrote S0
    hipLaunchKernelGGL(out_proj, dim3(BB), dim3(256), 0, stream, S0, Why, bp, out);
}

// Round 9
// 1412.319 us; speedup vs baseline: 1.7851x; 1.0805x over previous
//
#include <hip/hip_runtime.h>
#include <cstdint>
#include <cstddef>
#include <cmath>

#define H  2048
#define BB 2048   // batch
#define TT 64     // time steps
#define NC 10     // classes

typedef __bf16 bf16;
typedef bf16  bf16x8 __attribute__((ext_vector_type(8)));
typedef float f32x4  __attribute__((ext_vector_type(4)));

// ---------------------------------------------------------------------------
// async global->LDS, 16B per lane. LDS dest is wave-uniform base + lane*16;
// global source is per-lane.
// ---------------------------------------------------------------------------
__device__ __forceinline__ void load_lds16(const void* g, void* l) {
    __builtin_amdgcn_global_load_lds(
        (__attribute__((address_space(1))) void*)(void*)g,
        (__attribute__((address_space(3))) void*)l,
        16, 0, 0);
}

// ---------------------------------------------------------------------------
// FRAG-MAJOR layout (W_hh and S, since R12).
// For a matrix [R rows][H k-cols] (bf16):
//   subtile (r16, k32) = 16 rows x 32 k = 1024 B at id = r16*(H/32) + k32.
//   lane-slot l (16 B) holds M[r16*16 + (l&15)][k32*32 + (l>>4)*8 .. +8]
// = exactly the v_mfma_f32_16x16x32_bf16 A/B fragment, so a wave's frag load
// is ONE coalesced 1 KB segment: base + id*512 + lane*8 (bf16 elems).
// ---------------------------------------------------------------------------
__global__ void w_shuffle_kernel(const float* __restrict__ Whh,
                                 bf16* __restrict__ Wshuf) {
    int tid = blockIdx.x * blockDim.x + threadIdx.x;   // 0 .. H*H/8-1
    int sub = tid >> 6;          // subtile id
    int l   = tid & 63;          // dest lane slot
    int n16 = sub >> 6;          // 0..127
    int k32 = sub & 63;          // 0..63
    int n = n16 * 16 + (l & 15);
    int k = k32 * 32 + (l >> 4) * 8;
    const float* src = Whh + (size_t)n * H + k;
    bf16x8 o;
#pragma unroll
    for (int j = 0; j < 8; ++j) o[j] = (bf16)src[j];
    *(bf16x8*)(Wshuf + (size_t)tid * 8) = o;
}

// ---------------------------------------------------------------------------
// t = 0: S[b,i] = tanh(Whx[i]*x[b,0] + bh[i]), written FRAG-MAJOR.
// ---------------------------------------------------------------------------
__global__ void rnn_init(const float* __restrict__ x,     // [B, T]
                         const float* __restrict__ Whx,   // [H]
                         const float* __restrict__ bh,    // [H]
                         bf16* __restrict__ S) {          // frag-major
    int b  = blockIdx.x;
    int i0 = threadIdx.x * 8;
    float xv = x[(size_t)b * TT];
    bf16x8 o;
#pragma unroll
    for (int j = 0; j < 8; ++j)
        o[j] = (bf16)tanhf(Whx[i0 + j] * xv + bh[i0 + j]);
    size_t sub  = (size_t)(b >> 4) * 64 + (i0 >> 5);
    size_t slot = (size_t)(b & 15) | (size_t)(((i0 >> 3) & 3) << 4);
    *(bf16x8*)(S + (sub * 64 + slot) * 8) = o;
}

// ---------------------------------------------------------------------------
// One RNN time step, Round-19 "read-ahead fragment pipeline":
//   Sw[b,i] = tanh( sum_k Sr[b,k]*W[i,k] + Whx[i]*x[b,t] + bh[i] )
//
// R18 post-mortem: LDS-amplification theory refuted (96 vs 128 KB/phase =
// no change). The invariant cost is the EXPOSED ds_read issue+latency chain
// inside each phase: [barrier -> ds_read -> lgkm wait -> MFMA] serializes
// ~1100+ cy/phase vs 620 cy of MFMA. Fix: consume fragments read ONE PHASE
// EARLIER; read next phase's fragments during this phase's MFMAs.
//
//   - Protocol per phase p: s_waitcnt vmcnt(4)  [stages p AND p+1 resident;
//     issue depth unchanged at 3], s_barrier, ISSUE(p+3), ds_read slot(p+1)
//     -> R_next (ping-pong regs Ae/Be <-> Ao/Bo, all static), MFMA on R_cur.
//     ds_reads + stage issue hide under the 620 cy MFMA stretch; next
//     phase's MFMAs start right after the barrier (operands ~600 cy old).
//   - Slot safety: write slot (p+3)&3 = (p-1)&3, last ds_read in phase p-2,
//     two barriers ago. Concurrent read slot (p+1)&3 differs by 2 mod 4.
//   - Tail: p29 wait4 (30 ready), p30 wait0 (31 ready), p31 compute-only.
//   - Geometry/reduction/epilogue identical to R18 (8 waves split-K,
//     64x64 quadrants, XCD-owns-n, pair reduction) -> absmax unchanged.
// ---------------------------------------------------------------------------
#define PH_WAIT(NSTR) asm volatile("s_waitcnt vmcnt(" NSTR ")" ::: "memory")
#define SBAR0()       __builtin_amdgcn_sched_barrier(0)

__launch_bounds__(512, 2)
__global__ void rnn_step(const float* __restrict__ x,     // [B, T]
                         const float* __restrict__ Whx,   // [H]
                         const float* __restrict__ bh,    // [H]
                         const bf16*  __restrict__ Wshuf, // frag-major W_hh
                         const bf16*  __restrict__ Sr,    // frag-major S read
                         bf16* __restrict__ Sw,           // frag-major S write
                         int t) {
    // ring slot = 32 segs x 1 KB:
    //   segs  0..7  = A m16 0..7, chunk-lo   segs  8..15 = B n16 0..7, lo
    //   segs 16..23 = A m16 0..7, chunk-hi   segs 24..31 = B n16 0..7, hi
    __shared__ __align__(16) char Ls[4][32768];   // 128 KB -> 1 block/CU

    const int tid  = threadIdx.x;
    const int w    = tid >> 6;          // wave 0..7
    const int lane = tid & 63;
    const int lrow = lane & 15;
    const int quad = lane >> 4;

    // XCD-owns-n mapping: XCD x covers n-cols [x*256, x*256+256).
    const int xcd = blockIdx.x & 7;
    const int loc = blockIdx.x >> 3;               // 0..31
    const int bm0 = (loc >> 1) * 128;              // batch-row tile origin
    const int bn0 = xcd * 256 + (loc & 1) * 128;   // hidden-col tile origin

    const int kh   = w >> 2;                       // K-half (0: k<1024)
    const int s    = w & 3;                        // quadrant id
    const int qm   = s & 1;                        // m-quadrant (64 rows)
    const int qn   = s >> 1;                       // n-quadrant (64 cols)
    const int cn0  = bn0 + qn * 64;                // wave's first col
    const int kh16 = kh * 16;                      // seg offset of own half

    // staging sources (per wave): wave w owns A m16 subtile (bm0>>4)+w and
    // B n16 subtile (bn0>>4)+w, BOTH k-halves. 1 KB per k32, +lane*16B.
    const char* srcA = (const char*)Sr +
        ((size_t)((bm0 >> 4) + w) * 64) * 1024 + (size_t)lane * 16;
    const char* srcB = (const char*)Wshuf +
        ((size_t)((bn0 >> 4) + w) * 64) * 1024 + (size_t)lane * 16;

    f32x4 acc[4][4];
#pragma unroll
    for (int i = 0; i < 4; ++i)
#pragma unroll
        for (int j = 0; j < 4; ++j) acc[i][j] = (f32x4){0.f, 0.f, 0.f, 0.f};

    // fragment ping-pong banks (static names; rule #20)
    bf16x8 Ae[4], Be[4], Ao[4], Bo[4];

    // ---- issue section for phase pp into ring slot RI (4 VMEM ops) ----
#define ISSUE(RI, pp)                                                        \
    {                                                                        \
        load_lds16(srcA + (size_t)(pp) * 1024,        &Ls[RI][w * 1024]);    \
        load_lds16(srcB + (size_t)(pp) * 1024,        &Ls[RI][(8 + w) * 1024]); \
        load_lds16(srcA + (size_t)(32 + (pp)) * 1024, &Ls[RI][(16 + w) * 1024]); \
        load_lds16(srcB + (size_t)(32 + (pp)) * 1024, &Ls[RI][(24 + w) * 1024]); \
    }

    // ---- read fragments of ring slot RI into bank (Ax, Bx) ----
#define DSREAD(Ax, Bx, RI)                                                   \
    {                                                                        \
        _Pragma("unroll")                                                    \
        for (int fm = 0; fm < 4; ++fm)                                       \
            Ax[fm] = *(const bf16x8*)&Ls[RI]                                 \
                [(kh16 + qm * 4 + fm) * 1024 + lane * 16];                   \
        _Pragma("unroll")                                                    \
        for (int fn = 0; fn < 4; ++fn)                                       \
            Bx[fn] = *(const bf16x8*)&Ls[RI]                                 \
                [(kh16 + 8 + qn * 4 + fn) * 1024 + lane * 16];               \
    }

    // ---- 16 MFMAs on bank (Ax, Bx) ----
#define MFMAS(Ax, Bx)                                                        \
    {                                                                        \
        __builtin_amdgcn_s_setprio(1);                                       \
        _Pragma("unroll")                                                    \
        for (int fm = 0; fm < 4; ++fm)                                       \
            _Pragma("unroll")                                                \
            for (int fn = 0; fn < 4; ++fn)                                   \
                acc[fm][fn] = __builtin_amdgcn_mfma_f32_16x16x32_bf16(       \
                    Ax[fm], Bx[fn], acc[fm][fn], 0, 0, 0);                   \
        __builtin_amdgcn_s_setprio(0);                                       \
    }

    // phase p: wait W, barrier, issue p+3 (DOISS), read slot RNext into
    // next bank (DOREAD), MFMA on current bank.
#define PHASE(RNext, RIss, p, W, DOISS, DOREAD, AN, BN, AC, BC)              \
    {                                                                        \
        PH_WAIT(W);                                                          \
        SBAR0();                                                             \
        __builtin_amdgcn_s_barrier();                                        \
        SBAR0();                                                             \
        if (DOISS) ISSUE(RIss, (p) + 3);                                     \
        if (DOREAD) DSREAD(AN, BN, RNext);                                   \
        MFMAS(AC, BC);                                                       \
    }

    // prologue: issue phases 0,1,2; wait phase-0 landed; pre-read slot 0.
    ISSUE(0, 0); SBAR0();
    ISSUE(1, 1); SBAR0();
    ISSUE(2, 2); SBAR0();
    PH_WAIT("8");
    SBAR0();
    __builtin_amdgcn_s_barrier();
    SBAR0();
    DSREAD(Ae, Be, 0);

    // main loop: phases 0..27 (7 macro-iters x 4), steady wait = 4
#pragma unroll 1
    for (int q = 0; q < 7; ++q) {
        int p = 4 * q;
        PHASE(1, 3, p + 0, "4", 1, 1, Ao, Bo, Ae, Be);
        PHASE(2, 0, p + 1, "4", 1, 1, Ae, Be, Ao, Bo);
        PHASE(3, 1, p + 2, "4", 1, 1, Ao, Bo, Ae, Be);
        PHASE(0, 2, p + 3, "4", 1, 1, Ae, Be, Ao, Bo);
    }
    // peeled tail: phases 28..31
    PHASE(1, 3, 28, "4", 1, 1, Ao, Bo, Ae, Be);   // issues phase 31 -> slot3
    PHASE(2, 0, 29, "4", 0, 1, Ae, Be, Ao, Bo);
    PHASE(3, 1, 30, "0", 0, 1, Ao, Bo, Ae, Be);
    PHASE(0, 2, 31, "0", 0, 0, Ae, Be, Ao, Bo);   // compute-only

#undef PHASE
#undef MFMAS
#undef DSREAD
#undef ISSUE

    // ---- split-K pair reduction (slots 0-1; all gload_lds drained) ----
    // ALL acc indices below are compile-time constants (rule #20).
    // kh=0 donates fm{2,3}; kh=1 donates fm{0,1}; own = kept + partner.
    char* red = &Ls[0][0];
    const int pairbase = s * 16384;
    if (kh == 0) {
#pragma unroll
        for (int fml = 0; fml < 2; ++fml)
#pragma unroll
            for (int fn = 0; fn < 4; ++fn)
                *(f32x4*)&red[pairbase + (fml * 4 + fn) * 1024 + lane * 16] =
                    acc[2 + fml][fn];
    } else {
#pragma unroll
        for (int fml = 0; fml < 2; ++fml)
#pragma unroll
            for (int fn = 0; fn < 4; ++fn)
                *(f32x4*)&red[pairbase + 8192 + (fml * 4 + fn) * 1024 +
                              lane * 16] = acc[fml][fn];
    }
    __syncthreads();
    f32x4 own[2][4];
    if (kh == 0) {
#pragma unroll
        for (int fml = 0; fml < 2; ++fml)
#pragma unroll
            for (int fn = 0; fn < 4; ++fn)
                own[fml][fn] = acc[fml][fn] + *(const f32x4*)&red[pairbase +
                    8192 + (fml * 4 + fn) * 1024 + lane * 16];
    } else {
#pragma unroll
        for (int fml = 0; fml < 2; ++fml)
#pragma unroll
            for (int fn = 0; fn < 4; ++fn)
                own[fml][fn] = acc[2 + fml][fn] + *(const f32x4*)&red[pairbase +
                    (fml * 4 + fn) * 1024 + lane * 16];
    }

    // ---- epilogue on OWNED rows: z += Whx*x + bh; tanh; transpose ----
    // acc layout (16x16x32): col = lane&15, row = quad*4 + reg [m89-verified]
    // Owned global fm = kh*2 + fml (address math only; own[] is static-idx).
    // Transpose scratch: slot 2, wave-private 32 rows x 128 B, XOR-swizzled.
    bf16* Lw = (bf16*)&Ls[2][0] + (size_t)w * 2048;
#pragma unroll
    for (int fml = 0; fml < 2; ++fml) {
        int rb = bm0 + qm * 64 + (kh * 2 + fml) * 16 + quad * 4;
        float xv[4];
#pragma unroll
        for (int r = 0; r < 4; ++r) xv[r] = x[(size_t)(rb + r) * TT + t];
#pragma unroll
        for (int fn = 0; fn < 4; ++fn) {
            int col = cn0 + fn * 16 + lrow;
            float wx = Whx[col], bb = bh[col];
            int cbyte = (fn * 16 + lrow) * 2;
#pragma unroll
            for (int r = 0; r < 4; ++r) {
                int row_l = fml * 16 + quad * 4 + r;
                float z = own[fml][fn][r] + wx * xv[r] + bb;
                *(bf16*)((char*)Lw + row_l * 128 +
                         (cbyte ^ ((row_l & 7) << 4))) = (bf16)tanhf(z);
            }
        }
    }
    // read own wave's tile in frag-slot order; 16B coalesced global stores.
#pragma unroll
    for (int fml = 0; fml < 2; ++fml) {
#pragma unroll
        for (int kc = 0; kc < 2; ++kc) {
            int row_l = fml * 16 + lrow;
            int cb    = (kc * 64 + quad * 16) ^ ((row_l & 7) << 4);
            bf16x8 v = *(const bf16x8*)((const char*)Lw + row_l * 128 + cb);
            size_t sub = (size_t)((bm0 >> 4) + qm * 4 + kh * 2 + fml) * 64 +
                         (cn0 >> 5) + kc;
            *(bf16x8*)(Sw + (sub * 64 + lane) * 8) = v;
        }
    }
}

// ---------------------------------------------------------------------------
// out[b,c] = sum_h Why[h,c] * S[b,h] + bp[c]   (S frag-major)
// ---------------------------------------------------------------------------
__global__ void out_proj(const bf16* __restrict__ S,
                         const float* __restrict__ Why,   // [H, C]
                         const float* __restrict__ bp,    // [C]
                         float* __restrict__ out) {       // [B, C]
    int b = blockIdx.x, tid = threadIdx.x;
    int h0 = tid * 8;                                     // 256*8 = H exactly
    size_t sub  = (size_t)(b >> 4) * 64 + (h0 >> 5);
    size_t slot = (size_t)(b & 15) | (size_t)(((h0 >> 3) & 3) << 4);
    bf16x8 v = *(const bf16x8*)(S + (sub * 64 + slot) * 8);
    float p[NC];
#pragma unroll
    for (int c = 0; c < NC; ++c) p[c] = 0.f;
#pragma unroll
    for (int j = 0; j < 8; ++j) {
        float s = (float)v[j];
        const float* wr = Why + (size_t)(h0 + j) * NC;
#pragma unroll
        for (int c = 0; c < NC; ++c) p[c] += s * wr[c];
    }
    __shared__ float red[256 * NC];
#pragma unroll
    for (int c = 0; c < NC; ++c) red[tid * NC + c] = p[c];
    __syncthreads();
    for (int s = 128; s > 0; s >>= 1) {
        if (tid < s)
#pragma unroll
            for (int c = 0; c < NC; ++c) red[tid * NC + c] += red[(tid + s) * NC + c];
        __syncthreads();
    }
    if (tid < NC) out[(size_t)b * NC + tid] = red[tid] + bp[tid];
}

// ---------------------------------------------------------------------------
extern "C" void kernel_launch(void* const* d_in, const int* in_sizes, int n_in,
                              void* d_out, int out_size, void* d_ws, size_t ws_size,
                              hipStream_t stream) {
    const float* x   = (const float*)d_in[0];   // [B, T]
    const float* Whx = (const float*)d_in[1];   // [H, 1]
    const float* Whh = (const float*)d_in[2];   // [H, H]
    const float* Why = (const float*)d_in[3];   // [H, C]
    const float* bh  = (const float*)d_in[4];   // [H, 1]
    const float* bp  = (const float*)d_in[5];   // [C, 1]
    float* out = (float*)d_out;

    // workspace: Wshuf (8 MB) | S0 (8 MB) | S1 (8 MB)   (all frag-major)
    bf16* Wshuf = (bf16*)d_ws;
    bf16* S0 = (bf16*)((char*)d_ws + (size_t)8 * 1024 * 1024);
    bf16* S1 = (bf16*)((char*)d_ws + (size_t)16 * 1024 * 1024);

    hipLaunchKernelGGL(w_shuffle_kernel, dim3((H * H / 8) / 256), dim3(256),
                       0, stream, Whh, Wshuf);

    // t = 0 writes S1; step t reads (t&1 ? S1 : S0), writes the other.
    hipLaunchKernelGGL(rnn_init, dim3(BB), dim3(256), 0, stream, x, Whx, bh, S1);

    for (int t = 1; t < TT; ++t) {
        const bf16* Srd = (t & 1) ? S1 : S0;
        bf16*       Swr = (t & 1) ? S0 : S1;
        hipLaunchKernelGGL(rnn_step, dim3(256), dim3(512), 0, stream,
                           x, Whx, bh, Wshuf, Srd, Swr, t);
    }

    // t=63 (odd) wrote S0
    hipLaunchKernelGGL(out_proj, dim3(BB), dim3(256), 0, stream, S0, Why, bp, out);
}